// Round 10
// baseline (27.320 us; speedup 1.0000x reference)
//
#include <hip/hip_runtime.h>
#include <hip/hip_bf16.h>
#include <math.h>

#define NS 512
#define OD 128
#define BB 64
#define TT 2000
#define KK 400
#define CHUNK 128
#define NCH 16
#define LOG2PI_F 1.8378770664093453f

// ws layout (floats): [0,512) row_lse, [512] init_lse. Nothing else.

__device__ __forceinline__ float softplusf(float x) {
    return (x > 20.f) ? x : log1pf(expf(x));
}

// Lanczos log-gamma (NR gammln, float). |err| ~1e-6 rel for x>0 — far under
// the 1e4 absmax threshold; avoids the fat library lgammaf.
__device__ __forceinline__ float gammlnf(float x) {
    float tmp = x + 5.5f;
    tmp -= (x + 0.5f) * __logf(tmp);
    const float ser = 1.000000000190015f
        + 76.18009172947146f    / (x + 1.f)
        - 86.50532032941677f    / (x + 2.f)
        + 24.01409824083091f    / (x + 3.f)
        - 1.231739572450155f    / (x + 4.f)
        + 1.208650973866179e-3f / (x + 5.f)
        - 5.395239384953e-6f    / (x + 6.f);
    return -tmp + __logf(2.5066282746310005f * ser / x);
}

// K1: 512 transition-row LSEs + init LSE + zero out[]. 513 blocks.
__global__ __launch_bounds__(256) void k1_kernel(
    const float* __restrict__ trans, const float* __restrict__ init_logits,
    float* __restrict__ ws, float* __restrict__ out)
{
    const int tid = threadIdx.x;
    const int bid = blockIdx.x;
    __shared__ float red[4];

    if (bid == NS && tid < BB) out[tid] = 0.f;   // clean accumulators for K2

    const float* src = (bid < NS) ? (trans + (size_t)bid * NS) : init_logits;
    float x0 = src[tid];
    float x1 = src[tid + 256];
    float m = fmaxf(x0, x1);
    for (int off = 32; off; off >>= 1) m = fmaxf(m, __shfl_down(m, off, 64));
    if ((tid & 63) == 0) red[tid >> 6] = m;
    __syncthreads();
    m = fmaxf(fmaxf(red[0], red[1]), fmaxf(red[2], red[3]));
    __syncthreads();
    float e = __expf(x0 - m) + __expf(x1 - m);
    for (int off = 32; off; off >>= 1) e += __shfl_down(e, off, 64);
    if ((tid & 63) == 0) red[tid >> 6] = e;
    __syncthreads();
    if (tid == 0)
        ws[(bid < NS) ? bid : 512] = m + __logf(red[0] + red[1] + red[2] + red[3]);
}

// K2: 1024 obs blocks + 64 seq blocks; every block atomicAdds into out[b].
// No fences: contributions are independent sums, visibility at kernel end.
__global__ __launch_bounds__(256) void k2_kernel(
    const float* __restrict__ obs, const float* __restrict__ mu,
    const float* __restrict__ lvar, const float* __restrict__ trans,
    const float* __restrict__ init_logits,
    const float* __restrict__ alpha_p, const float* __restrict__ beta_p,
    const int* __restrict__ states, const int* __restrict__ durs,
    const float* __restrict__ ws, float* __restrict__ out)
{
    const int tid = threadIdx.x;
    const int bid = blockIdx.x;
    __shared__ float red[4];

    if (bid < BB * NCH) {
        // ---- observation partial for (batch b, 128-frame chunk) ----
        const int b = bid >> 4;
        const int t0 = (bid & 15) * CHUNK;

        __shared__ int fsl[CHUNK];
        __shared__ int csum[8];

        // states+durations -> registers; wave-shuffle inclusive scan of durs
        const int lane = tid & 63, w = tid >> 6;
        int s0v = states[b * KK + tid];            // tid < 400 always
        int d0  = durs[b * KK + tid];
        int s1v = 0, d1 = 0;
        if (tid + 256 < KK) {
            s1v = states[b * KK + tid + 256];
            d1  = durs[b * KK + tid + 256];
        }
        int v0 = d0, v1 = d1;
        #pragma unroll
        for (int off = 1; off < 64; off <<= 1) {
            int u0 = __shfl_up(v0, off, 64);
            int u1 = __shfl_up(v1, off, 64);
            if (lane >= off) { v0 += u0; v1 += u1; }
        }
        if (lane == 63) { csum[w] = v0; csum[4 + w] = v1; }
        __syncthreads();
        int off0 = 0, off1 = 0;
        #pragma unroll
        for (int c = 0; c < 8; ++c) {
            int cs = csum[c];
            off0 += (c < w) ? cs : 0;
            off1 += (c < 4 + w) ? cs : 0;
        }
        const int c0 = v0 + off0;      // cum[tid]
        const int c1 = v1 + off1;      // cum[tid+256]

        // interval-expand: thread k writes its segment's frames in this chunk.
        {
            int a = c0 - d0, e = c0;
            a = (a < t0) ? t0 : a;
            e = (e > t0 + CHUNK) ? t0 + CHUNK : e;
            for (int t = a; t < e; ++t) fsl[t - t0] = s0v;
            int a1 = c1 - d1, e1 = (tid + 256 == KK - 1) ? t0 + CHUNK : c1;
            a1 = (a1 < t0) ? t0 : a1;
            e1 = (e1 > t0 + CHUNK) ? t0 + CHUNK : e1;
            for (int t = a1; t < e1; ++t) fsl[t - t0] = s1v;
        }
        __syncthreads();

        const int row = tid >> 5;          // 8 frames per iter
        const int dd = (tid & 31) * 4;
        float acc = 0.f;
        if (t0 + CHUNK <= TT) {
            #pragma unroll
            for (int i = 0; i < CHUNK / 8; ++i) {
                const int t = t0 + i * 8 + row;
                const int s = fsl[i * 8 + row];
                const float4 o  = *(const float4*)(obs + ((size_t)(b * TT + t)) * OD + dd);
                const float4 m  = *(const float4*)(mu  + (size_t)s * OD + dd);
                const float4 lv = *(const float4*)(lvar + (size_t)s * OD + dd);
                const float dx = o.x - m.x, dy = o.y - m.y, dz = o.z - m.z, dw = o.w - m.w;
                acc += lv.x + lv.y + lv.z + lv.w + 4.f * LOG2PI_F
                     + dx * dx * __expf(-lv.x) + dy * dy * __expf(-lv.y)
                     + dz * dz * __expf(-lv.z) + dw * dw * __expf(-lv.w);
            }
        } else {
            #pragma unroll
            for (int i = 0; i < CHUNK / 8; ++i) {
                const int t = t0 + i * 8 + row;
                if (t < TT) {
                    const int s = fsl[i * 8 + row];
                    const float4 o  = *(const float4*)(obs + ((size_t)(b * TT + t)) * OD + dd);
                    const float4 m  = *(const float4*)(mu  + (size_t)s * OD + dd);
                    const float4 lv = *(const float4*)(lvar + (size_t)s * OD + dd);
                    const float dx = o.x - m.x, dy = o.y - m.y, dz = o.z - m.z, dw = o.w - m.w;
                    acc += lv.x + lv.y + lv.z + lv.w + 4.f * LOG2PI_F
                         + dx * dx * __expf(-lv.x) + dy * dy * __expf(-lv.y)
                         + dz * dz * __expf(-lv.z) + dw * dw * __expf(-lv.w);
                }
            }
        }
        for (int off = 32; off; off >>= 1) acc += __shfl_down(acc, off, 64);
        if ((tid & 63) == 0) red[tid >> 6] = acc;
        __syncthreads();
        if (tid == 0)
            atomicAdd(out + b, -0.5f * (red[0] + red[1] + red[2] + red[3]));
    } else {
        // ---- seq: duration + (trans numerator - row_lse) + init, per batch ----
        const int b = bid - BB * NCH;
        float lp = 0.f;
        for (int k = tid; k < KK; k += 256) {
            const int s = states[b * KK + k];
            const float dv = (float)durs[b * KK + k];
            const float a  = softplusf(alpha_p[s]) + 1e-6f;
            const float bt = softplusf(beta_p[s]) + 1e-6f;
            float v = (a - 1.f) * __logf(dv + 1e-8f) - bt * dv
                    + a * __logf(bt) - gammlnf(a);
            lp += (dv >= 1.f) ? v : -INFINITY;
            if (k < KK - 1)
                lp += trans[(size_t)s * NS + states[b * KK + k + 1]] - ws[s];
        }
        if (tid == 0)
            lp += init_logits[states[b * KK]] - ws[512];
        for (int off = 32; off; off >>= 1) lp += __shfl_down(lp, off, 64);
        if ((tid & 63) == 0) red[tid >> 6] = lp;
        __syncthreads();
        if (tid == 0)
            atomicAdd(out + b, red[0] + red[1] + red[2] + red[3]);
    }
}

extern "C" void kernel_launch(void* const* d_in, const int* in_sizes, int n_in,
                              void* d_out, int out_size, void* d_ws, size_t ws_size,
                              hipStream_t stream) {
    const float* observations = (const float*)d_in[0];
    const float* alpha_p      = (const float*)d_in[1];
    const float* beta_p       = (const float*)d_in[2];
    const float* trans        = (const float*)d_in[3];
    const float* init_logits  = (const float*)d_in[4];
    const float* obs_means    = (const float*)d_in[5];
    const float* obs_logvars  = (const float*)d_in[6];
    const int*   state_seq    = (const int*)d_in[7];
    const int*   dur_seq      = (const int*)d_in[8];

    float* ws = (float*)d_ws;
    float* out = (float*)d_out;

    k1_kernel<<<NS + 1, 256, 0, stream>>>(trans, init_logits, ws, out);
    k2_kernel<<<BB * NCH + BB, 256, 0, stream>>>(
        observations, obs_means, obs_logvars, trans, init_logits,
        alpha_p, beta_p, state_seq, dur_seq, ws, out);
}

// Round 11
// 22.408 us; speedup vs baseline: 1.2192x; 1.2192x over previous
//
#include <hip/hip_runtime.h>
#include <hip/hip_bf16.h>
#include <math.h>

#define NS 512
#define OD 128
#define BB 64
#define TT 2000
#define KK 400
#define CHUNK 128
#define NCH 16
#define LOG2PI_F 1.8378770664093453f
#define SEQ_OFF  576      // ws float offset: per-batch seq partials [BB]
#define PART_OFF 1024     // ws float offset: obs partials [BB*NCH]

// ws layout (floats):
//   [0,512) row_lse   [512] init_lse
//   [SEQ_OFF,+64)   duration + trans-numerator + init_logit partial per batch
//   [PART_OFF,+1024) obs partials (scaled by -0.5)

__device__ __forceinline__ float softplusf(float x) {
    return (x > 20.f) ? x : log1pf(expf(x));
}

// Lanczos log-gamma (verified absmax 0.0 in R10); leaner than lib lgammaf,
// keeps the unified kernel under the 64-VGPR cap for 32 waves/CU.
__device__ __forceinline__ float gammlnf(float x) {
    float tmp = x + 5.5f;
    tmp -= (x + 0.5f) * __logf(tmp);
    const float ser = 1.000000000190015f
        + 76.18009172947146f    / (x + 1.f)
        - 86.50532032941677f    / (x + 2.f)
        + 24.01409824083091f    / (x + 3.f)
        - 1.231739572450155f    / (x + 4.f)
        + 1.208650973866179e-3f / (x + 5.f)
        - 5.395239384953e-6f    / (x + 6.f);
    return -tmp + __logf(2.5066282746310005f * ser / x);
}

// grid (512-thr blocks): [0,1024) obs | [1024,1537) lse | [1537,1601) seq
// 512 thr/block -> 4 blocks/CU -> 32 waves/CU (100% occupancy; VGPR<=64).
__global__ __launch_bounds__(512, 8) void big_kernel(
    const float* __restrict__ obs, const float* __restrict__ mu,
    const float* __restrict__ lvar, const float* __restrict__ trans,
    const float* __restrict__ init_logits,
    const float* __restrict__ alpha_p, const float* __restrict__ beta_p,
    const int* __restrict__ states, const int* __restrict__ durs,
    float* __restrict__ ws)
{
    const int tid = threadIdx.x;
    const int bid = blockIdx.x;
    __shared__ float red[8];

    if (bid < BB * NCH) {
        // ---- observation partial for (batch b, 128-frame chunk) ----
        const int b = bid >> 4;
        const int t0 = (bid & 15) * CHUNK;

        __shared__ int fsl[CHUNK];
        __shared__ int csum[8];

        // one scan element per thread (tid<400); wave-shuffle inclusive scan
        const int lane = tid & 63, w = tid >> 6;
        int sv = 0, dv = 0;
        if (tid < KK) { sv = states[b * KK + tid]; dv = durs[b * KK + tid]; }
        int v = dv;
        #pragma unroll
        for (int off = 1; off < 64; off <<= 1) {
            int u = __shfl_up(v, off, 64);
            if (lane >= off) v += u;
        }
        if (lane == 63) csum[w] = v;
        __syncthreads();
        int woff = 0;
        #pragma unroll
        for (int c = 0; c < 8; ++c) woff += (c < w) ? csum[c] : 0;
        const int cum = v + woff;          // inclusive cumsum at k=tid

        // interval-expand this thread's segment into the chunk window
        if (tid < KK) {
            int a = cum - dv;
            int e = (tid == KK - 1) ? t0 + CHUNK : cum;   // last seg -> +inf
            a = (a < t0) ? t0 : a;
            e = (e > t0 + CHUNK) ? t0 + CHUNK : e;
            for (int t = a; t < e; ++t) fsl[t - t0] = sv;
        }
        __syncthreads();

        const int row = tid >> 5;          // 0..15 -> 16 frames per iter
        const int dd = (tid & 31) * 4;
        float acc = 0.f;
        if (t0 + CHUNK <= TT) {
            #pragma unroll
            for (int i = 0; i < CHUNK / 16; ++i) {
                const int t = t0 + i * 16 + row;
                const int s = fsl[i * 16 + row];
                const float4 o  = *(const float4*)(obs + ((size_t)(b * TT + t)) * OD + dd);
                const float4 m  = *(const float4*)(mu  + (size_t)s * OD + dd);
                const float4 lv = *(const float4*)(lvar + (size_t)s * OD + dd);
                const float dx = o.x - m.x, dy = o.y - m.y, dz = o.z - m.z, dw = o.w - m.w;
                acc += lv.x + lv.y + lv.z + lv.w + 4.f * LOG2PI_F
                     + dx * dx * __expf(-lv.x) + dy * dy * __expf(-lv.y)
                     + dz * dz * __expf(-lv.z) + dw * dw * __expf(-lv.w);
            }
        } else {
            #pragma unroll
            for (int i = 0; i < CHUNK / 16; ++i) {
                const int t = t0 + i * 16 + row;
                if (t < TT) {
                    const int s = fsl[i * 16 + row];
                    const float4 o  = *(const float4*)(obs + ((size_t)(b * TT + t)) * OD + dd);
                    const float4 m  = *(const float4*)(mu  + (size_t)s * OD + dd);
                    const float4 lv = *(const float4*)(lvar + (size_t)s * OD + dd);
                    const float dx = o.x - m.x, dy = o.y - m.y, dz = o.z - m.z, dw = o.w - m.w;
                    acc += lv.x + lv.y + lv.z + lv.w + 4.f * LOG2PI_F
                         + dx * dx * __expf(-lv.x) + dy * dy * __expf(-lv.y)
                         + dz * dz * __expf(-lv.z) + dw * dw * __expf(-lv.w);
                }
            }
        }
        for (int off = 32; off; off >>= 1) acc += __shfl_down(acc, off, 64);
        if ((tid & 63) == 0) red[tid >> 6] = acc;
        __syncthreads();
        if (tid == 0) {
            float s = 0.f;
            #pragma unroll
            for (int c = 0; c < 8; ++c) s += red[c];
            ws[PART_OFF + bid] = -0.5f * s;
        }
    } else if (bid < BB * NCH + NS + 1) {
        // ---- LSE: transition row r<512, or initial logits (r==512) ----
        const int r = bid - BB * NCH;
        const float* src = (r < NS) ? (trans + (size_t)r * NS) : init_logits;
        const float x = src[tid];               // 512 threads, 512 elems
        float m = x;
        for (int off = 32; off; off >>= 1) m = fmaxf(m, __shfl_down(m, off, 64));
        if ((tid & 63) == 0) red[tid >> 6] = m;
        __syncthreads();
        m = red[0];
        #pragma unroll
        for (int c = 1; c < 8; ++c) m = fmaxf(m, red[c]);
        __syncthreads();
        float e = __expf(x - m);
        for (int off = 32; off; off >>= 1) e += __shfl_down(e, off, 64);
        if ((tid & 63) == 0) red[tid >> 6] = e;
        __syncthreads();
        if (tid == 0) {
            float s = 0.f;
            #pragma unroll
            for (int c = 0; c < 8; ++c) s += red[c];
            ws[(r < NS) ? r : 512] = m + __logf(s);
        }
    } else {
        // ---- seq: duration terms + transition numerators + init logit ----
        const int b = bid - (BB * NCH + NS + 1);
        float lp = 0.f;
        if (tid < KK) {
            const int s = states[b * KK + tid];
            const float dvf = (float)durs[b * KK + tid];
            const float a  = softplusf(alpha_p[s]) + 1e-6f;
            const float bt = softplusf(beta_p[s]) + 1e-6f;
            float vv = (a - 1.f) * __logf(dvf + 1e-8f) - bt * dvf
                     + a * __logf(bt) - gammlnf(a);
            lp = (dvf >= 1.f) ? vv : -INFINITY;
            if (tid < KK - 1)
                lp += trans[(size_t)s * NS + states[b * KK + tid + 1]];
        }
        for (int off = 32; off; off >>= 1) lp += __shfl_down(lp, off, 64);
        if ((tid & 63) == 0) red[tid >> 6] = lp;
        __syncthreads();
        if (tid == 0) {
            float s = 0.f;
            #pragma unroll
            for (int c = 0; c < 8; ++c) s += red[c];
            ws[SEQ_OFF + b] = s + init_logits[states[b * KK]];
        }
    }
}

__global__ __launch_bounds__(256) void fin_kernel(
    const int* __restrict__ states, const float* __restrict__ ws,
    float* __restrict__ out)
{
    const int b = blockIdx.x;
    const int tid = threadIdx.x;
    __shared__ float red[4];

    float lp = 0.f;
    if (tid < NCH)       lp = ws[PART_OFF + b * NCH + tid];
    else if (tid == NCH) lp = ws[SEQ_OFF + b] - ws[512];
    // subtract row_lse for each transition (2 KB table, L1-hot)
    for (int k = tid; k < KK - 1; k += 256)
        lp -= ws[states[b * KK + k]];
    for (int off = 32; off; off >>= 1) lp += __shfl_down(lp, off, 64);
    if ((tid & 63) == 0) red[tid >> 6] = lp;
    __syncthreads();
    if (tid == 0)
        out[b] = red[0] + red[1] + red[2] + red[3];
}

extern "C" void kernel_launch(void* const* d_in, const int* in_sizes, int n_in,
                              void* d_out, int out_size, void* d_ws, size_t ws_size,
                              hipStream_t stream) {
    const float* observations = (const float*)d_in[0];
    const float* alpha_p      = (const float*)d_in[1];
    const float* beta_p       = (const float*)d_in[2];
    const float* trans        = (const float*)d_in[3];
    const float* init_logits  = (const float*)d_in[4];
    const float* obs_means    = (const float*)d_in[5];
    const float* obs_logvars  = (const float*)d_in[6];
    const int*   state_seq    = (const int*)d_in[7];
    const int*   dur_seq      = (const int*)d_in[8];

    float* ws = (float*)d_ws;
    float* out = (float*)d_out;

    big_kernel<<<BB * NCH + NS + 1 + BB, 512, 0, stream>>>(
        observations, obs_means, obs_logvars, trans, init_logits,
        alpha_p, beta_p, state_seq, dur_seq, ws);
    fin_kernel<<<BB, 256, 0, stream>>>(state_seq, ws, out);
}